// Round 11
// baseline (1041.471 us; speedup 1.0000x reference)
//
#include <hip/hip_runtime.h>
#include <hip/hip_bf16.h>

// ---------------------------------------------------------------------------
// UFGConv: out = sum_b A_b * (filter_b . (A_b * (x @ W)))
// N=100000, F=128, E=3.2M per branch (3 branches).
// R11: col-bucket-sorted edges per row (scatter2 bins 512 -> 4096 =
//      512 rows x 8 col-windows of 4 MB = one XCD L2) so concurrent waves
//      sweep a narrow col window -> L2 hits instead of 15x re-fetch.
//      3 mid-SPMMs merged into spmm_mid3; single ginit3. out3 kept.
// ---------------------------------------------------------------------------

#define CHUNK 4096  // edges per scatter1 block
#define CITER 16    // CHUNK / 256
#define MAXC 256    // max coarse buckets (N <= 131072)

typedef __attribute__((ext_vector_type(8))) short short8;
typedef __attribute__((ext_vector_type(4))) float f32x4;

static __device__ __forceinline__ unsigned short bf16bits(float v) {
  return __builtin_bit_cast(unsigned short, __float2bfloat16(v));
}
static __device__ __forceinline__ float bflo(unsigned u) {
  return __uint_as_float(u << 16);
}
static __device__ __forceinline__ float bfhi(unsigned u) {
  return __uint_as_float(u & 0xffff0000u);
}

// MFMA GEMM: y[n][128] (bf16) = x[n][128] (f32) @ w[128][128] (f32).
__global__ __launch_bounds__(256) void gemm_mfma(const float* __restrict__ x,
                                                 const float* __restrict__ w,
                                                 unsigned short* __restrict__ y,
                                                 int n) {
  __shared__ unsigned short wt[128][136];  // W^T [col][k], pad 136
  const int tid = threadIdx.x;
#pragma unroll
  for (int it = 0; it < 16; ++it) {
    int i = it * 256 + tid;
    int k = i >> 5;
    int c4 = (i & 31) << 2;
    float4 v = ((const float4*)w)[i];
    wt[c4 + 0][k] = bf16bits(v.x);
    wt[c4 + 1][k] = bf16bits(v.y);
    wt[c4 + 2][k] = bf16bits(v.z);
    wt[c4 + 3][k] = bf16bits(v.w);
  }
  __syncthreads();
  const int lane = tid & 63, wid = tid >> 6;
  const int lr = lane & 15, lq = lane >> 4;
  const int rowbase = blockIdx.x * 128 + wid * 32;
  f32x4 acc[2][8] = {};
#pragma unroll
  for (int ks = 0; ks < 4; ++ks) {
    short8 a[2];
#pragma unroll
    for (int s = 0; s < 2; ++s) {
      int r = rowbase + s * 16 + lr;
      float4 v0 = {0.f, 0.f, 0.f, 0.f}, v1 = {0.f, 0.f, 0.f, 0.f};
      if (r < n) {
        const float* xp = x + (size_t)r * 128 + ks * 32 + lq * 8;
        v0 = *(const float4*)xp;
        v1 = *(const float4*)(xp + 4);
      }
      a[s][0] = bf16bits(v0.x);
      a[s][1] = bf16bits(v0.y);
      a[s][2] = bf16bits(v0.z);
      a[s][3] = bf16bits(v0.w);
      a[s][4] = bf16bits(v1.x);
      a[s][5] = bf16bits(v1.y);
      a[s][6] = bf16bits(v1.z);
      a[s][7] = bf16bits(v1.w);
    }
#pragma unroll
    for (int cs = 0; cs < 8; ++cs) {
      short8 b = *(const short8*)&wt[cs * 16 + lr][ks * 32 + lq * 8];
      acc[0][cs] =
          __builtin_amdgcn_mfma_f32_16x16x32_bf16(a[0], b, acc[0][cs], 0, 0, 0);
      acc[1][cs] =
          __builtin_amdgcn_mfma_f32_16x16x32_bf16(a[1], b, acc[1][cs], 0, 0, 0);
    }
  }
#pragma unroll
  for (int s = 0; s < 2; ++s) {
#pragma unroll
    for (int cs = 0; cs < 8; ++cs) {
      int col = cs * 16 + lr;
      int r0 = rowbase + s * 16 + lq * 4;
#pragma unroll
      for (int j = 0; j < 4; ++j) {
        int r = r0 + j;
        if (r < n) y[(size_t)r * 128 + col] = bf16bits(acc[s][cs][j]);
      }
    }
  }
}

// Init all 3 branches' per-bucket append cursors.
__global__ void ginit3(int* __restrict__ gcur, int NC, int CAP) {
  int i = blockIdx.x * 256 + threadIdx.x;
  if (i < 3 * NC) gcur[(i / NC) * MAXC + (i % NC)] = (i % NC) * CAP;
}

// Block-aggregated coarse scatter into fixed-capacity bucket regions.
__global__ __launch_bounds__(256) void scatter1(const int* __restrict__ rows,
                                                const int* __restrict__ cols,
                                                const float* __restrict__ vals,
                                                int* __restrict__ gcur,
                                                int2* __restrict__ st1, int E,
                                                int NC) {
  __shared__ int lh[MAXC], gb[MAXC], lc[MAXC];
  __shared__ int rc[CHUNK];
  const int tid = threadIdx.x;
  lh[tid] = 0;
  __syncthreads();
  const int base = blockIdx.x * CHUNK;
#pragma unroll
  for (int k = 0; k < CITER; ++k) {
    int e = base + k * 256 + tid;
    int r = -1;
    if (e < E) {
      r = __builtin_nontemporal_load(rows + e);
      atomicAdd(&lh[r >> 9], 1);
    }
    rc[k * 256 + tid] = r;
  }
  __syncthreads();
  if (tid < NC) {
    int n = lh[tid];
    gb[tid] = n ? atomicAdd(&gcur[tid], n) : 0;
    lc[tid] = 0;
  }
  __syncthreads();
#pragma unroll
  for (int k = 0; k < CITER; ++k) {
    int e = base + k * 256 + tid;
    int r = rc[k * 256 + tid];
    if (r >= 0) {
      int c = r >> 9;
      int off = atomicAdd(&lc[c], 1);
      int2 o;
      o.x = ((r & 511) << 17) | __builtin_nontemporal_load(cols + e);
      o.y = __float_as_int(__builtin_nontemporal_load(vals + e));
      st1[gb[c] + off] = o;
    }
  }
}

// Refine each coarse bucket into (row x 8 col-window) bins; emit per-row
// {start,end}. Edges land row-contiguous, col-window-sorted within the row.
__global__ __launch_bounds__(512) void scatter2(const int* __restrict__ gcur,
                                                const int2* __restrict__ st1,
                                                int2* __restrict__ st2,
                                                int2* __restrict__ rowse,
                                                int CAP) {
  __shared__ int cnt[4096], cur[4096], ssc[512];
  const int c = blockIdx.x, tid = threadIdx.x;
  const int a = c * CAP;
  const int b = gcur[c];  // a + count
  for (int i = tid; i < 4096; i += 512) cnt[i] = 0;
  __syncthreads();
  for (int e = a + tid; e < b; e += 512) {
    int x = st1[e].x;
    atomicAdd(&cnt[(((x >> 17) & 511) << 3) | ((x >> 14) & 7)], 1);
  }
  __syncthreads();
  const int base = tid << 3;
  int loc[8], s = 0;
#pragma unroll
  for (int j = 0; j < 8; ++j) {
    loc[j] = cnt[base + j];
    s += loc[j];
  }
  ssc[tid] = s;
  __syncthreads();
  for (int o = 1; o < 512; o <<= 1) {
    int t2 = (tid >= o) ? ssc[tid - o] : 0;
    __syncthreads();
    ssc[tid] += t2;
    __syncthreads();
  }
  int ex = ssc[tid] - s;  // exclusive prefix (row tid's start in bucket)
  int run = ex;
#pragma unroll
  for (int j = 0; j < 8; ++j) {
    cur[base + j] = a + run;
    run += loc[j];
  }
  rowse[(c << 9) + tid] = make_int2(a + ex, a + ex + s);
  __syncthreads();
  for (int e = a + tid; e < b; e += 512) {
    int2 d = st1[e];
    int bin = (((d.x >> 17) & 511) << 3) | ((d.x >> 14) & 7);
    int p = atomicAdd(&cur[bin], 1);
    st2[p] = make_int2(d.x & 0x1FFFF, d.y);
  }
}

// Gather-dot for one row's edge range: 8-deep (R7 operating point).
static __device__ __forceinline__ void row_dot(
    int e, int e1, const int2* __restrict__ edges,
    const unsigned short* __restrict__ src, unsigned loff, float& a0,
    float& a1) {
  for (; e + 7 < e1; e += 8) {
    int4 p0 = *(const int4*)&edges[e];
    int4 p1 = *(const int4*)&edges[e + 2];
    int4 p2 = *(const int4*)&edges[e + 4];
    int4 p3 = *(const int4*)&edges[e + 6];
    unsigned u0 = *(const unsigned*)(src + (((size_t)p0.x) << 7) + loff);
    unsigned u1 = *(const unsigned*)(src + (((size_t)p0.z) << 7) + loff);
    unsigned u2 = *(const unsigned*)(src + (((size_t)p1.x) << 7) + loff);
    unsigned u3 = *(const unsigned*)(src + (((size_t)p1.z) << 7) + loff);
    unsigned u4 = *(const unsigned*)(src + (((size_t)p2.x) << 7) + loff);
    unsigned u5 = *(const unsigned*)(src + (((size_t)p2.z) << 7) + loff);
    unsigned u6 = *(const unsigned*)(src + (((size_t)p3.x) << 7) + loff);
    unsigned u7 = *(const unsigned*)(src + (((size_t)p3.z) << 7) + loff);
    float v0 = __int_as_float(p0.y), v1 = __int_as_float(p0.w);
    float v2 = __int_as_float(p1.y), v3 = __int_as_float(p1.w);
    float v4 = __int_as_float(p2.y), v5 = __int_as_float(p2.w);
    float v6 = __int_as_float(p3.y), v7 = __int_as_float(p3.w);
    a0 += v0 * bflo(u0);
    a1 += v0 * bfhi(u0);
    a0 += v1 * bflo(u1);
    a1 += v1 * bfhi(u1);
    a0 += v2 * bflo(u2);
    a1 += v2 * bfhi(u2);
    a0 += v3 * bflo(u3);
    a1 += v3 * bfhi(u3);
    a0 += v4 * bflo(u4);
    a1 += v4 * bfhi(u4);
    a0 += v5 * bflo(u5);
    a1 += v5 * bfhi(u5);
    a0 += v6 * bflo(u6);
    a1 += v6 * bfhi(u6);
    a0 += v7 * bflo(u7);
    a1 += v7 * bfhi(u7);
  }
  for (; e < e1; ++e) {
    int2 d = edges[e];
    unsigned u = *(const unsigned*)(src + (((size_t)d.x) << 7) + loff);
    float v = __int_as_float(d.y);
    a0 += v * bflo(u);
    a1 += v * bfhi(u);
  }
}

// Per-branch SPMM (fallback path). MID: dst=filt*(A*src). !MID: out (=/+=).
template <int MID>
__global__ __launch_bounds__(256) void spmm_w(
    const int2* __restrict__ rowse, const int2* __restrict__ edges,
    const unsigned short* __restrict__ src, unsigned short* __restrict__ dst,
    float* __restrict__ out, const float* __restrict__ filt, int N, int accm) {
  const int lane = threadIdx.x & 63, wid = threadIdx.x >> 6;
  const int row = blockIdx.x * 4 + wid;
  if (row >= N) return;
  const int2 se = rowse[row];
  float a0 = 0.f, a1 = 0.f;
  const unsigned loff = (unsigned)(lane << 1);
  row_dot(se.x, se.y, edges, src, loff, a0, a1);
  if (MID) {
    float fl = filt[row];
    a0 *= fl;
    a1 *= fl;
    unsigned o = (unsigned)bf16bits(a0) | ((unsigned)bf16bits(a1) << 16);
    *(unsigned*)(dst + ((size_t)row << 7) + loff) = o;
  } else {
    float* op = out + ((size_t)row << 7) + loff;
    float2 r;
    r.x = a0;
    r.y = a1;
    if (accm) {
      float2 c = *(const float2*)op;
      r.x += c.x;
      r.y += c.y;
    }
    *(float2*)op = r;
  }
}

// Fused mid-pass: t_b = bf16(filt_b . (A_b * xW)) for b=0..2, one dispatch.
__global__ __launch_bounds__(256) void spmm_mid3(
    const int2* __restrict__ rs0, const int2* __restrict__ rs1,
    const int2* __restrict__ rs2, const int2* __restrict__ e0,
    const int2* __restrict__ e1, const int2* __restrict__ e2,
    const unsigned short* __restrict__ xW, unsigned short* __restrict__ t0,
    unsigned short* __restrict__ t1, unsigned short* __restrict__ t2,
    const float* __restrict__ f0, const float* __restrict__ f1,
    const float* __restrict__ f2, int N) {
  const int lane = threadIdx.x & 63, wid = threadIdx.x >> 6;
  const int row = blockIdx.x * 4 + wid;
  if (row >= N) return;
  const unsigned loff = (unsigned)(lane << 1);
  const size_t po = ((size_t)row << 7) + loff;
  int2 s;
  float a0, a1, fl;
  unsigned o;
  s = rs0[row];
  a0 = a1 = 0.f;
  row_dot(s.x, s.y, e0, xW, loff, a0, a1);
  fl = f0[row];
  o = (unsigned)bf16bits(a0 * fl) | ((unsigned)bf16bits(a1 * fl) << 16);
  *(unsigned*)(t0 + po) = o;
  s = rs1[row];
  a0 = a1 = 0.f;
  row_dot(s.x, s.y, e1, xW, loff, a0, a1);
  fl = f1[row];
  o = (unsigned)bf16bits(a0 * fl) | ((unsigned)bf16bits(a1 * fl) << 16);
  *(unsigned*)(t1 + po) = o;
  s = rs2[row];
  a0 = a1 = 0.f;
  row_dot(s.x, s.y, e2, xW, loff, a0, a1);
  fl = f2[row];
  o = (unsigned)bf16bits(a0 * fl) | ((unsigned)bf16bits(a1 * fl) << 16);
  *(unsigned*)(t2 + po) = o;
}

// Fused out-pass: out = A1*t1 + A2*t2 + A3*t3 (single write, no RMW).
__global__ __launch_bounds__(256) void spmm_out3(
    const int2* __restrict__ rs1, const int2* __restrict__ rs2,
    const int2* __restrict__ rs3, const int2* __restrict__ e1,
    const int2* __restrict__ e2, const int2* __restrict__ e3,
    const unsigned short* __restrict__ t1, const unsigned short* __restrict__ t2,
    const unsigned short* __restrict__ t3, float* __restrict__ out, int N) {
  const int lane = threadIdx.x & 63, wid = threadIdx.x >> 6;
  const int row = blockIdx.x * 4 + wid;
  if (row >= N) return;
  float a0 = 0.f, a1 = 0.f;
  const unsigned loff = (unsigned)(lane << 1);
  int2 s;
  s = rs1[row];
  row_dot(s.x, s.y, e1, t1, loff, a0, a1);
  s = rs2[row];
  row_dot(s.x, s.y, e2, t2, loff, a0, a1);
  s = rs3[row];
  row_dot(s.x, s.y, e3, t3, loff, a0, a1);
  float2 r;
  r.x = a0;
  r.y = a1;
  *(float2*)(out + ((size_t)row << 7) + loff) = r;
}

extern "C" void kernel_launch(void* const* d_in, const int* in_sizes, int n_in,
                              void* d_out, int out_size, void* d_ws, size_t ws_size,
                              hipStream_t stream) {
  const float* x = (const float*)d_in[0];
  const float* w = (const float*)d_in[1];
  const float* filt[3] = {(const float*)d_in[2], (const float*)d_in[3],
                          (const float*)d_in[4]};
  const int* idx[3] = {(const int*)d_in[5], (const int*)d_in[7],
                       (const int*)d_in[9]};
  const float* val[3] = {(const float*)d_in[6], (const float*)d_in[8],
                         (const float*)d_in[10]};
  const int N = in_sizes[2];
  const int E = in_sizes[6];
  float* out = (float*)d_out;

  const int NC = (N + 511) >> 9;  // coarse buckets (512 rows each)
  // Capacity: mean + 2048 (~16 sigma for binomial bucket counts).
  const int CAP = (((E + NC - 1) / NC) + 2048 + 255) & ~255;
  const size_t NF16 = (size_t)N * 128 * sizeof(unsigned short);
  const size_t STB = (size_t)NC * CAP * 8;  // one st array
  const size_t RSB = ((size_t)(NC << 9) * 8 + 255) & ~(size_t)255;
  const size_t GCB = (3 * MAXC * 4 + 255) & ~(size_t)255;

  // Fused layout: xW, t1..t3, st1, st2 x3, rowse x3, gcur(3 branches).
  const size_t need_fused = 4 * NF16 + 4 * STB + 3 * RSB + GCB;
  const bool fused = (ws_size >= need_fused);

  char* ws = (char*)d_ws;
  const int gE = (E + CHUNK - 1) / CHUNK;
  const int gS = (N + 3) / 4;

  if (fused) {
    unsigned short* xW = (unsigned short*)ws;
    unsigned short* t[3];
    t[0] = (unsigned short*)(ws + NF16);
    t[1] = (unsigned short*)(ws + 2 * NF16);
    t[2] = (unsigned short*)(ws + 3 * NF16);
    size_t off = 4 * NF16;
    int2* st1 = (int2*)(ws + off);
    off += STB;
    int2* st2[3];
    for (int b = 0; b < 3; ++b) {
      st2[b] = (int2*)(ws + off);
      off += STB;
    }
    int2* rowse[3];
    for (int b = 0; b < 3; ++b) {
      rowse[b] = (int2*)(ws + off);
      off += RSB;
    }
    int* gcur = (int*)(ws + off);

    ginit3<<<(3 * NC + 255) / 256, 256, 0, stream>>>(gcur, NC, CAP);
    gemm_mfma<<<(N + 127) / 128, 256, 0, stream>>>(x, w, xW, N);
    for (int b = 0; b < 3; ++b) {
      scatter1<<<gE, 256, 0, stream>>>(idx[b], idx[b] + E, val[b],
                                       gcur + b * MAXC, st1, E, NC);
      scatter2<<<NC, 512, 0, stream>>>(gcur + b * MAXC, st1, st2[b], rowse[b],
                                       CAP);
    }
    spmm_mid3<<<gS, 256, 0, stream>>>(rowse[0], rowse[1], rowse[2], st2[0],
                                      st2[1], st2[2], xW, t[0], t[1], t[2],
                                      filt[0], filt[1], filt[2], N);
    spmm_out3<<<gS, 256, 0, stream>>>(rowse[0], rowse[1], rowse[2], st2[0],
                                      st2[1], st2[2], t[0], t[1], t[2], out, N);
  } else {
    unsigned short* xW = (unsigned short*)ws;
    unsigned short* t = (unsigned short*)(ws + NF16);
    size_t off = 2 * NF16;
    int2* st1 = (int2*)(ws + off);
    off += STB;
    int2* st2 = (int2*)(ws + off);
    off += STB;
    int2* rowse = (int2*)(ws + off);
    off += RSB;
    int* gcur = (int*)(ws + off);

    ginit3<<<(3 * NC + 255) / 256, 256, 0, stream>>>(gcur, NC, CAP);
    gemm_mfma<<<(N + 127) / 128, 256, 0, stream>>>(x, w, xW, N);
    for (int b = 0; b < 3; ++b) {
      scatter1<<<gE, 256, 0, stream>>>(idx[b], idx[b] + E, val[b],
                                       gcur + b * MAXC, st1, E, NC);
      scatter2<<<NC, 512, 0, stream>>>(gcur + b * MAXC, st1, st2, rowse, CAP);
      spmm_w<1><<<gS, 256, 0, stream>>>(rowse, st2, xW, t, nullptr, filt[b], N,
                                        0);
      spmm_w<0><<<gS, 256, 0, stream>>>(rowse, st2, t, nullptr, out, nullptr,
                                        N, b > 0 ? 1 : 0);
    }
  }
}

// Round 12
// 1025.660 us; speedup vs baseline: 1.0154x; 1.0154x over previous
//
#include <hip/hip_runtime.h>
#include <hip/hip_bf16.h>

// ---------------------------------------------------------------------------
// UFGConv: out = sum_b A_b * (filter_b . (A_b * (x @ W)))
// N=100000, F=128, E=3.2M per branch (3 branches).
// R12: revert R11's col-window sort (falsified: FETCH unchanged 1.18 GB,
//      +15us scan cost). Back to R10 best-measured config: MFMA GEMM,
//      fixed-capacity hierarchical CSR build, per-branch mid SPMM (R7
//      8-deep operating point), fused out3 (no out RMW).
//      SPMM effective rate converged at 3.6-3.7 TB/s across 7 variants ->
//      random-gather pattern roofline.
// ---------------------------------------------------------------------------

#define CHUNK 4096  // edges per scatter1 block
#define CITER 16    // CHUNK / 256
#define MAXC 256    // max coarse buckets (N <= 131072)

typedef __attribute__((ext_vector_type(8))) short short8;
typedef __attribute__((ext_vector_type(4))) float f32x4;

static __device__ __forceinline__ unsigned short bf16bits(float v) {
  return __builtin_bit_cast(unsigned short, __float2bfloat16(v));
}
static __device__ __forceinline__ float bflo(unsigned u) {
  return __uint_as_float(u << 16);
}
static __device__ __forceinline__ float bfhi(unsigned u) {
  return __uint_as_float(u & 0xffff0000u);
}

// MFMA GEMM: y[n][128] (bf16) = x[n][128] (f32) @ w[128][128] (f32).
__global__ __launch_bounds__(256) void gemm_mfma(const float* __restrict__ x,
                                                 const float* __restrict__ w,
                                                 unsigned short* __restrict__ y,
                                                 int n) {
  __shared__ unsigned short wt[128][136];  // W^T [col][k], pad 136
  const int tid = threadIdx.x;
#pragma unroll
  for (int it = 0; it < 16; ++it) {
    int i = it * 256 + tid;
    int k = i >> 5;
    int c4 = (i & 31) << 2;
    float4 v = ((const float4*)w)[i];
    wt[c4 + 0][k] = bf16bits(v.x);
    wt[c4 + 1][k] = bf16bits(v.y);
    wt[c4 + 2][k] = bf16bits(v.z);
    wt[c4 + 3][k] = bf16bits(v.w);
  }
  __syncthreads();
  const int lane = tid & 63, wid = tid >> 6;
  const int lr = lane & 15, lq = lane >> 4;
  const int rowbase = blockIdx.x * 128 + wid * 32;
  f32x4 acc[2][8] = {};
#pragma unroll
  for (int ks = 0; ks < 4; ++ks) {
    short8 a[2];
#pragma unroll
    for (int s = 0; s < 2; ++s) {
      int r = rowbase + s * 16 + lr;
      float4 v0 = {0.f, 0.f, 0.f, 0.f}, v1 = {0.f, 0.f, 0.f, 0.f};
      if (r < n) {
        const float* xp = x + (size_t)r * 128 + ks * 32 + lq * 8;
        v0 = *(const float4*)xp;
        v1 = *(const float4*)(xp + 4);
      }
      a[s][0] = bf16bits(v0.x);
      a[s][1] = bf16bits(v0.y);
      a[s][2] = bf16bits(v0.z);
      a[s][3] = bf16bits(v0.w);
      a[s][4] = bf16bits(v1.x);
      a[s][5] = bf16bits(v1.y);
      a[s][6] = bf16bits(v1.z);
      a[s][7] = bf16bits(v1.w);
    }
#pragma unroll
    for (int cs = 0; cs < 8; ++cs) {
      short8 b = *(const short8*)&wt[cs * 16 + lr][ks * 32 + lq * 8];
      acc[0][cs] =
          __builtin_amdgcn_mfma_f32_16x16x32_bf16(a[0], b, acc[0][cs], 0, 0, 0);
      acc[1][cs] =
          __builtin_amdgcn_mfma_f32_16x16x32_bf16(a[1], b, acc[1][cs], 0, 0, 0);
    }
  }
#pragma unroll
  for (int s = 0; s < 2; ++s) {
#pragma unroll
    for (int cs = 0; cs < 8; ++cs) {
      int col = cs * 16 + lr;
      int r0 = rowbase + s * 16 + lq * 4;
#pragma unroll
      for (int j = 0; j < 4; ++j) {
        int r = r0 + j;
        if (r < n) y[(size_t)r * 128 + col] = bf16bits(acc[s][cs][j]);
      }
    }
  }
}

// Init per-bucket append cursors to bucket bases.
__global__ void ginit(int* __restrict__ gcur, int NC, int CAP) {
  int i = blockIdx.x * 256 + threadIdx.x;
  if (i < NC) gcur[i] = i * CAP;
}

// Block-aggregated coarse scatter into fixed-capacity bucket regions.
__global__ __launch_bounds__(256) void scatter1(const int* __restrict__ rows,
                                                const int* __restrict__ cols,
                                                const float* __restrict__ vals,
                                                int* __restrict__ gcur,
                                                int2* __restrict__ st1, int E,
                                                int NC) {
  __shared__ int lh[MAXC], gb[MAXC], lc[MAXC];
  __shared__ int rc[CHUNK];
  const int tid = threadIdx.x;
  lh[tid] = 0;
  __syncthreads();
  const int base = blockIdx.x * CHUNK;
#pragma unroll
  for (int k = 0; k < CITER; ++k) {
    int e = base + k * 256 + tid;
    int r = -1;
    if (e < E) {
      r = __builtin_nontemporal_load(rows + e);
      atomicAdd(&lh[r >> 9], 1);
    }
    rc[k * 256 + tid] = r;
  }
  __syncthreads();
  if (tid < NC) {
    int n = lh[tid];
    gb[tid] = n ? atomicAdd(&gcur[tid], n) : 0;
    lc[tid] = 0;
  }
  __syncthreads();
#pragma unroll
  for (int k = 0; k < CITER; ++k) {
    int e = base + k * 256 + tid;
    int r = rc[k * 256 + tid];
    if (r >= 0) {
      int c = r >> 9;
      int off = atomicAdd(&lc[c], 1);
      int2 o;
      o.x = ((r & 511) << 17) | __builtin_nontemporal_load(cols + e);
      o.y = __float_as_int(__builtin_nontemporal_load(vals + e));
      st1[gb[c] + off] = o;
    }
  }
}

// Refine each coarse bucket into exact rows; emit per-row {start,end}.
__global__ __launch_bounds__(512) void scatter2(const int* __restrict__ gcur,
                                                const int2* __restrict__ st1,
                                                int2* __restrict__ st2,
                                                int2* __restrict__ rowse,
                                                int CAP) {
  __shared__ int sh[512], cur[512];
  const int c = blockIdx.x, tid = threadIdx.x;
  const int a = c * CAP;
  const int b = gcur[c];  // a + count
  sh[tid] = 0;
  __syncthreads();
  for (int e = a + tid; e < b; e += 512)
    atomicAdd(&sh[(st1[e].x >> 17) & 511], 1);
  __syncthreads();
  int v = sh[tid];
  __syncthreads();
  for (int o = 1; o < 512; o <<= 1) {
    int t2 = (tid >= o) ? sh[tid - o] : 0;
    __syncthreads();
    sh[tid] += t2;
    __syncthreads();
  }
  int end = a + sh[tid];
  int start = end - v;
  cur[tid] = start;
  rowse[(c << 9) + tid] = make_int2(start, end);
  __syncthreads();
  for (int e = a + tid; e < b; e += 512) {
    int2 d = st1[e];
    int r = (d.x >> 17) & 511;
    int p = atomicAdd(&cur[r], 1);
    st2[p] = make_int2(d.x & 0x1FFFF, d.y);
  }
}

// Gather-dot for one row's edge range: 8-deep (R7 operating point).
static __device__ __forceinline__ void row_dot(
    int e, int e1, const int2* __restrict__ edges,
    const unsigned short* __restrict__ src, unsigned loff, float& a0,
    float& a1) {
  for (; e + 7 < e1; e += 8) {
    int4 p0 = *(const int4*)&edges[e];
    int4 p1 = *(const int4*)&edges[e + 2];
    int4 p2 = *(const int4*)&edges[e + 4];
    int4 p3 = *(const int4*)&edges[e + 6];
    unsigned u0 = *(const unsigned*)(src + (((size_t)p0.x) << 7) + loff);
    unsigned u1 = *(const unsigned*)(src + (((size_t)p0.z) << 7) + loff);
    unsigned u2 = *(const unsigned*)(src + (((size_t)p1.x) << 7) + loff);
    unsigned u3 = *(const unsigned*)(src + (((size_t)p1.z) << 7) + loff);
    unsigned u4 = *(const unsigned*)(src + (((size_t)p2.x) << 7) + loff);
    unsigned u5 = *(const unsigned*)(src + (((size_t)p2.z) << 7) + loff);
    unsigned u6 = *(const unsigned*)(src + (((size_t)p3.x) << 7) + loff);
    unsigned u7 = *(const unsigned*)(src + (((size_t)p3.z) << 7) + loff);
    float v0 = __int_as_float(p0.y), v1 = __int_as_float(p0.w);
    float v2 = __int_as_float(p1.y), v3 = __int_as_float(p1.w);
    float v4 = __int_as_float(p2.y), v5 = __int_as_float(p2.w);
    float v6 = __int_as_float(p3.y), v7 = __int_as_float(p3.w);
    a0 += v0 * bflo(u0);
    a1 += v0 * bfhi(u0);
    a0 += v1 * bflo(u1);
    a1 += v1 * bfhi(u1);
    a0 += v2 * bflo(u2);
    a1 += v2 * bfhi(u2);
    a0 += v3 * bflo(u3);
    a1 += v3 * bfhi(u3);
    a0 += v4 * bflo(u4);
    a1 += v4 * bfhi(u4);
    a0 += v5 * bflo(u5);
    a1 += v5 * bfhi(u5);
    a0 += v6 * bflo(u6);
    a1 += v6 * bfhi(u6);
    a0 += v7 * bflo(u7);
    a1 += v7 * bfhi(u7);
  }
  for (; e < e1; ++e) {
    int2 d = edges[e];
    unsigned u = *(const unsigned*)(src + (((size_t)d.x) << 7) + loff);
    float v = __int_as_float(d.y);
    a0 += v * bflo(u);
    a1 += v * bfhi(u);
  }
}

// SPMM: one wave per row; lane owns features {2l,2l+1} (256 B/gather).
// MID: dst(bf16)=filt[row]*(A*src).  !MID: out(f32) (=/+=) A*src.
template <int MID>
__global__ __launch_bounds__(256) void spmm_w(
    const int2* __restrict__ rowse, const int2* __restrict__ edges,
    const unsigned short* __restrict__ src, unsigned short* __restrict__ dst,
    float* __restrict__ out, const float* __restrict__ filt, int N, int accm) {
  const int lane = threadIdx.x & 63, wid = threadIdx.x >> 6;
  const int row = blockIdx.x * 4 + wid;
  if (row >= N) return;
  const int2 se = rowse[row];
  float a0 = 0.f, a1 = 0.f;
  const unsigned loff = (unsigned)(lane << 1);
  row_dot(se.x, se.y, edges, src, loff, a0, a1);
  if (MID) {
    float fl = filt[row];
    a0 *= fl;
    a1 *= fl;
    unsigned o = (unsigned)bf16bits(a0) | ((unsigned)bf16bits(a1) << 16);
    *(unsigned*)(dst + ((size_t)row << 7) + loff) = o;
  } else {
    float* op = out + ((size_t)row << 7) + loff;
    float2 r;
    r.x = a0;
    r.y = a1;
    if (accm) {
      float2 c = *(const float2*)op;
      r.x += c.x;
      r.y += c.y;
    }
    *(float2*)op = r;
  }
}

// Fused out-pass over all 3 branches: out = A1*t1 + A2*t2 + A3*t3 (one write).
__global__ __launch_bounds__(256) void spmm_out3(
    const int2* __restrict__ rs1, const int2* __restrict__ rs2,
    const int2* __restrict__ rs3, const int2* __restrict__ e1,
    const int2* __restrict__ e2, const int2* __restrict__ e3,
    const unsigned short* __restrict__ t1, const unsigned short* __restrict__ t2,
    const unsigned short* __restrict__ t3, float* __restrict__ out, int N) {
  const int lane = threadIdx.x & 63, wid = threadIdx.x >> 6;
  const int row = blockIdx.x * 4 + wid;
  if (row >= N) return;
  float a0 = 0.f, a1 = 0.f;
  const unsigned loff = (unsigned)(lane << 1);
  int2 s;
  s = rs1[row];
  row_dot(s.x, s.y, e1, t1, loff, a0, a1);
  s = rs2[row];
  row_dot(s.x, s.y, e2, t2, loff, a0, a1);
  s = rs3[row];
  row_dot(s.x, s.y, e3, t3, loff, a0, a1);
  float2 r;
  r.x = a0;
  r.y = a1;
  *(float2*)(out + ((size_t)row << 7) + loff) = r;
}

extern "C" void kernel_launch(void* const* d_in, const int* in_sizes, int n_in,
                              void* d_out, int out_size, void* d_ws, size_t ws_size,
                              hipStream_t stream) {
  const float* x = (const float*)d_in[0];
  const float* w = (const float*)d_in[1];
  const float* filt[3] = {(const float*)d_in[2], (const float*)d_in[3],
                          (const float*)d_in[4]};
  const int* idx[3] = {(const int*)d_in[5], (const int*)d_in[7],
                       (const int*)d_in[9]};
  const float* val[3] = {(const float*)d_in[6], (const float*)d_in[8],
                         (const float*)d_in[10]};
  const int N = in_sizes[2];
  const int E = in_sizes[6];
  float* out = (float*)d_out;

  const int NC = (N + 511) >> 9;  // coarse buckets (512 rows each)
  // Capacity: mean + 2048 (~16 sigma for binomial bucket counts).
  const int CAP = (((E + NC - 1) / NC) + 2048 + 255) & ~255;
  const size_t NF16 = (size_t)N * 128 * sizeof(unsigned short);
  const size_t STB = (size_t)NC * CAP * 8;           // one st array
  const size_t RSB = ((size_t)(NC << 9) * 8 + 255) & ~(size_t)255;
  const size_t GCB = (MAXC * 4 + 255) & ~(size_t)255;

  // Fused layout: xW, t1..t3, st1, st2 x3, rowse x3, gcur.
  const size_t need_fused = 4 * NF16 + 4 * STB + 3 * RSB + GCB;
  const bool fused = (ws_size >= need_fused);

  char* ws = (char*)d_ws;
  const int gE = (E + CHUNK - 1) / CHUNK;
  const int gS = (N + 3) / 4;

  if (fused) {
    unsigned short* xW = (unsigned short*)ws;
    unsigned short* t[3];
    t[0] = (unsigned short*)(ws + NF16);
    t[1] = (unsigned short*)(ws + 2 * NF16);
    t[2] = (unsigned short*)(ws + 3 * NF16);
    size_t off = 4 * NF16;
    int2* st1 = (int2*)(ws + off);
    off += STB;
    int2* st2[3];
    for (int b = 0; b < 3; ++b) {
      st2[b] = (int2*)(ws + off);
      off += STB;
    }
    int2* rowse[3];
    for (int b = 0; b < 3; ++b) {
      rowse[b] = (int2*)(ws + off);
      off += RSB;
    }
    int* gcur = (int*)(ws + off);

    gemm_mfma<<<(N + 127) / 128, 256, 0, stream>>>(x, w, xW, N);
    for (int b = 0; b < 3; ++b) {
      ginit<<<(NC + 255) / 256, 256, 0, stream>>>(gcur, NC, CAP);
      scatter1<<<gE, 256, 0, stream>>>(idx[b], idx[b] + E, val[b], gcur, st1,
                                       E, NC);
      scatter2<<<NC, 512, 0, stream>>>(gcur, st1, st2[b], rowse[b], CAP);
    }
    for (int b = 0; b < 3; ++b)
      spmm_w<1><<<gS, 256, 0, stream>>>(rowse[b], st2[b], xW, t[b], nullptr,
                                        filt[b], N, 0);
    spmm_out3<<<gS, 256, 0, stream>>>(rowse[0], rowse[1], rowse[2], st2[0],
                                      st2[1], st2[2], t[0], t[1], t[2], out, N);
  } else {
    unsigned short* xW = (unsigned short*)ws;
    unsigned short* t = (unsigned short*)(ws + NF16);
    size_t off = 2 * NF16;
    int2* st1 = (int2*)(ws + off);
    off += STB;
    int2* st2 = (int2*)(ws + off);
    off += STB;
    int2* rowse = (int2*)(ws + off);
    off += RSB;
    int* gcur = (int*)(ws + off);

    gemm_mfma<<<(N + 127) / 128, 256, 0, stream>>>(x, w, xW, N);
    for (int b = 0; b < 3; ++b) {
      ginit<<<(NC + 255) / 256, 256, 0, stream>>>(gcur, NC, CAP);
      scatter1<<<gE, 256, 0, stream>>>(idx[b], idx[b] + E, val[b], gcur, st1,
                                       E, NC);
      scatter2<<<NC, 512, 0, stream>>>(gcur, st1, st2, rowse, CAP);
      spmm_w<1><<<gS, 256, 0, stream>>>(rowse, st2, xW, t, nullptr, filt[b], N,
                                        0);
      spmm_w<0><<<gS, 256, 0, stream>>>(rowse, st2, t, nullptr, out, nullptr,
                                        N, b > 0 ? 1 : 0);
    }
  }
}